// Round 10
// baseline (11705.567 us; speedup 1.0000x reference)
//
#include <hip/hip_runtime.h>
#include <stdint.h>
#include <stddef.h>

// Problem constants
constexpr int V = 32000, E = 256, H = 512, B = 64, T = 512;
constexpr int NTHR = 512;        // 8 waves
constexpr int NBLK = 128;        // 8 XCD slots x 16; blk%8<4 real, rest exit
constexpr int BATG = 16;         // batches per group
constexpr int HPB = 32;          // hidden units per block (128 gate rows)

// LDS: Pg gate-packed partials [8 waves][jloc32][batch16][gate4] f32 (64KB)
//      + Bias4 + Lens + HX remap + Obuf
constexpr int PGW = 2048;                           // floats per wave
constexpr int OFF_PG   = 0;                         // 65536
constexpr int OFF_BIAS = 65536;                     // 128 f32 (512B)
constexpr int OFF_LEN  = 66048;                     // 16 ints
constexpr int OFF_HX   = 66112;                     // 16*66 f32 = 4224B
constexpr int OFF_OBUF = 70400;                     // 8*512 f32 = 16KB
constexpr int LDS_BYTES = 88 * 1024;                // 1 block/CU

// Output layout (flat fp32): output | hT | cT | mask
constexpr size_t OUT_HT   = (size_t)B * T * H;
constexpr size_t OUT_CT   = OUT_HT + (size_t)B * H;
constexpr size_t OUT_MASK = OUT_CT + (size_t)B * H;

typedef __attribute__((ext_vector_type(8))) short short8;   // 8 bf16
typedef __attribute__((ext_vector_type(4))) float f32x4;
typedef __attribute__((ext_vector_type(4))) unsigned int u32x4;

__device__ __forceinline__ unsigned short f2bf(float f) {   // RNE fp32->bf16
  uint32_t u = __builtin_bit_cast(uint32_t, f);
  return (unsigned short)((u + 0x7fffu + ((u >> 16) & 1u)) >> 16);
}
__device__ __forceinline__ short8 pack_bf8(float4 v0, float4 v1) {
  short8 r;
  r[0] = (short)f2bf(v0.x); r[1] = (short)f2bf(v0.y);
  r[2] = (short)f2bf(v0.z); r[3] = (short)f2bf(v0.w);
  r[4] = (short)f2bf(v1.x); r[5] = (short)f2bf(v1.y);
  r[6] = (short)f2bf(v1.z); r[7] = (short)f2bf(v1.w);
  return r;
}
__device__ __forceinline__ float sigmoidf_fast(float x) {
  return 1.f / (1.f + __expf(-x));
}
__device__ __forceinline__ float tanhf_fast(float x) {   // 1 - 2/(e^2x+1)
  return 1.f - 2.f / (__expf(2.f * x) + 1.f);            // inf-safe both tails
}
__device__ __forceinline__ void bar_lgkm() {   // barrier w/o vmcnt drain
  asm volatile("s_waitcnt lgkmcnt(0)\n\ts_barrier" ::: "memory");
}
__device__ __forceinline__ void st_plain(uint32_t* p, uint32_t v) {
  asm volatile("global_store_dword %0, %1, off" :: "v"(p), "v"(v) : "memory");
}
__device__ __forceinline__ void st_sc1(uint32_t* p, uint32_t v) {
  asm volatile("global_store_dword %0, %1, off sc1" :: "v"(p), "v"(v) : "memory");
}
// 4x dwordx4 XCD-L2-coherent loads (sc0: bypass L1, hit shared L2)
__device__ __forceinline__ void ld_l2_k64(const uint32_t* p, u32x4& r0,
                                          u32x4& r1, u32x4& r2, u32x4& r3) {
  asm volatile(
      "global_load_dwordx4 %0, %4, off sc0\n\t"
      "global_load_dwordx4 %1, %4, off offset:16 sc0\n\t"
      "global_load_dwordx4 %2, %4, off offset:128 sc0\n\t"
      "global_load_dwordx4 %3, %4, off offset:144 sc0\n\t"
      "s_waitcnt vmcnt(0)"
      : "=&v"(r0), "=&v"(r1), "=&v"(r2), "=&v"(r3)
      : "v"(p)
      : "memory");
}
// 4x dwordx4 MALL-coherent loads (sc1) — fallback path
__device__ __forceinline__ void ld_mall_k64(const uint32_t* p, u32x4& r0,
                                            u32x4& r1, u32x4& r2, u32x4& r3) {
  asm volatile(
      "global_load_dwordx4 %0, %4, off sc1\n\t"
      "global_load_dwordx4 %1, %4, off offset:16 sc1\n\t"
      "global_load_dwordx4 %2, %4, off offset:128 sc1\n\t"
      "global_load_dwordx4 %3, %4, off offset:144 sc1\n\t"
      "s_waitcnt vmcnt(0)"
      : "=&v"(r0), "=&v"(r1), "=&v"(r2), "=&v"(r3)
      : "v"(p)
      : "memory");
}
// pack 8 tagged-fp32 dwords -> short8 bf16 frag via v_cvt_pk_bf16_f32 (RNE)
__device__ __forceinline__ short8 cvt_frag(u32x4 lo, u32x4 hi) {
  uint32_t d0, d1, d2, d3;
  asm("v_cvt_pk_bf16_f32 %0, %1, %2" : "=v"(d0) : "v"(lo[0]), "v"(lo[1]));
  asm("v_cvt_pk_bf16_f32 %0, %1, %2" : "=v"(d1) : "v"(lo[2]), "v"(lo[3]));
  asm("v_cvt_pk_bf16_f32 %0, %1, %2" : "=v"(d2) : "v"(hi[0]), "v"(hi[1]));
  asm("v_cvt_pk_bf16_f32 %0, %1, %2" : "=v"(d3) : "v"(hi[2]), "v"(hi[3]));
  u32x4 d = {d0, d1, d2, d3};
  return __builtin_bit_cast(short8, d);
}
#define MFMA16(a, b, c) __builtin_amdgcn_mfma_f32_16x16x32_bf16((a), (b), (c), 0, 0, 0)

__global__ void __launch_bounds__(NTHR, 1)
lstm_mfma(const int* __restrict__ inputs, const int* __restrict__ lengths,
          const int* __restrict__ resets, const float* __restrict__ emb,
          const float* __restrict__ W_ih, const float* __restrict__ W_hh,
          const float* __restrict__ b_ih, const float* __restrict__ b_hh,
          float* __restrict__ out, uint32_t* __restrict__ hL2,
          uint32_t* __restrict__ hML) {
  const int tid = threadIdx.x;
  const int blk = blockIdx.x;
  const int grp = blk & 7;        // groups 0..3 real (XCD blk%8); 4..7 exit
  if (grp >= 4) return;

  extern __shared__ char lds[];
  float* Pg = (float*)(lds + OFF_PG);      // [w][jloc][batch][gate]
  float* Bias = (float*)(lds + OFF_BIAS);  // gate-packed [jloc][gate]
  int* Lens = (int*)(lds + OFF_LEN);
  float* HX = (float*)(lds + OFF_HX);      // [batch][66]: carry | h_next
  float* Obuf = (float*)(lds + OFF_OBUF);  // [8 steps][512 thr]

  const int rq = blk >> 3;        // block rank in group 0..15
  const int vblk = grp * 16 + rq;
  const int khid = rq * HPB;
  const int b0 = grp * BATG;

  const int w = tid >> 6;         // wave 0..7
  const int L = tid & 63;
  const int lc = L & 15;          // batch (B-frag col / A-frag row-in-tile)
  const int q = L >> 4;           // quad

  // ---- persistent W frags (bf16), 8-wave K-split + gate-packed rows:
  // A-frag tile row p = 16tl + lc encodes gate=p&3, jloc=p>>2;
  // grow = (p&3)*H + khid + (p>>2).  K: W_hh 64w+32s+8q; W_ih 32w+8q.
  // (fragment math correctness-proven in R4)
  short8 wfh[2][8];
  short8 wfe[8];
  #pragma unroll
  for (int s = 0; s < 2; ++s) {
    #pragma unroll
    for (int tl = 0; tl < 8; ++tl) {
      const int p = 16 * tl + lc;
      const int grow = (p & 3) * H + khid + (p >> 2);
      const float* src = W_hh + (size_t)grow * H + 64 * w + 32 * s + 8 * q;
      wfh[s][tl] = pack_bf8(*(const float4*)src, *(const float4*)(src + 4));
    }
  }
  #pragma unroll
  for (int tl = 0; tl < 8; ++tl) {
    const int p = 16 * tl + lc;
    const int grow = (p & 3) * H + khid + (p >> 2);
    const float* src = W_ih + (size_t)grow * E + 32 * w + 8 * q;
    wfe[tl] = pack_bf8(*(const float4*)src, *(const float4*)(src + 4));
  }
  if (tid < 128) {  // Bias gate-packed: idx = jloc*4 + g
    const int g = tid & 3, jl = tid >> 2;
    Bias[tid] = b_ih[g * H + khid + jl] + b_hh[g * H + khid + jl];
  }
  if (tid < 16) Lens[tid] = lengths[b0 + tid];
  {  // mask output, fused: 64 real blocks x 512 threads = B*T
    int i = vblk * 512 + tid;
    int mb = i >> 9, mt = i & (T - 1);
    out[OUT_MASK + i] = (mt < lengths[mb]) ? 1.f : 0.f;
  }
  __syncthreads();

  // epilogue (R4 map): thread owns (jloc = 4w+q, batch = lc)
  const int jloc = 4 * w + q;
  // store/Obuf (R5 map): coalesced full lines
  const int jj = tid & 31;
  const int bb = tid >> 5;

  float carry_h = 0.f, carry_c = 0.f;
  bool fb = false;                // sticky MALL fallback, armed t>=2 only
  uint32_t pend_bits = 0;         // deferred sc1 mirror payload
  size_t pend_doff = 0;

  // prologue prefetch for t=0 (lc-indexed: epilogue batch)
  float rr_cur = (float)resets[(b0 + lc) * T + 0];
  const float* eb0 =
      emb + (size_t)inputs[(b0 + lc) * T + 0] * E + 32 * w + 8 * q;
  float4 e0 = *(const float4*)eb0, e1 = *(const float4*)(eb0 + 4);

  for (int tb = 0; tb < T / 8; ++tb) {
    #pragma unroll 1
    for (int ts = 0; ts < 8; ++ts) {
      const int t = tb * 8 + ts;
      const size_t srcbase = (size_t)(t & 1) * (B * H);
      const size_t dstbase = (size_t)((t + 1) & 1) * (B * H);

      short8 ae = pack_bf8(e0, e1);
      const float rr = rr_cur;
      int tok_n = 0; float rr_n = 0.f;
      if (t < T - 1) {
        tok_n = inputs[(b0 + lc) * T + t + 1];
        rr_n = (float)resets[(b0 + lc) * T + t + 1];
      }

      // emb-side MFMA (swapped: A=W, B=act; accumulation order emb, h)
      f32x4 acc[8];
      const f32x4 zero4 = {0.f, 0.f, 0.f, 0.f};
      #pragma unroll
      for (int tl = 0; tl < 8; ++tl)
        acc[tl] = MFMA16(wfe[tl], ae, zero4);

      if (t > 0) {
        // tag-validated h read.  tag(t-1) = 4 | ((t-1)>>1 & 3).
        // L2 fast path; sticky MALL fallback armed only for t>=2 (64 spins)
        // -- at t==1 the slow-block preamble skew (~10-30us >> 64 spins)
        // would trip it spuriously (R2/R5 pathology).  Deferred sc1 mirror
        // of OUR previous step's word is issued at spin-48 or on detect:
        // inductive progress (everyone reaches poll(1) unconditionally).
        const uint32_t expect = 4u | (((uint32_t)(t - 1) >> 1) & 3u);
        const size_t off = srcbase + (size_t)(b0 + lc) * H + 64 * w + 8 * q;
        const uint32_t* pl2 = hL2 + off;
        const uint32_t* pml = hML + off;
        const int fbth = (t == 1) ? 4096 : 64;
        u32x4 r0, r1, r2, r3;
        int spins = 0;
        bool mirrored = false;
        for (;;) {
          if (!fb) ld_l2_k64(pl2, r0, r1, r2, r3);
          else     ld_mall_k64(pml, r0, r1, r2, r3);
          uint32_t o = (r0[0] | r0[1] | r0[2] | r0[3]) |
                       (r1[0] | r1[1] | r1[2] | r1[3]) |
                       (r2[0] | r2[1] | r2[2] | r2[3]) |
                       (r3[0] | r3[1] | r3[2] | r3[3]);
          uint32_t a = (r0[0] & r0[1] & r0[2] & r0[3]) &
                       (r1[0] & r1[1] & r1[2] & r1[3]) &
                       (r2[0] & r2[1] & r2[2] & r2[3]) &
                       (r3[0] & r3[1] & r3[2] & r3[3]);
          uint32_t bad = ((o ^ expect) | (a ^ expect)) & 7u;
          if (!__any((int)bad)) break;
          ++spins;
          if (!mirrored && spins >= 48) {       // progress guarantee
            st_sc1(hML + pend_doff, pend_bits);
            mirrored = true;
          }
          if (!fb && spins >= fbth) fb = true;
          if (spins >= 65536) break;            // watchdog: fail-visible
        }
        if (!mirrored) st_sc1(hML + pend_doff, pend_bits);  // off crit path

        short8 a0 = cvt_frag(r0, r1);   // K = 64w+8q    .. +8
        short8 a1 = cvt_frag(r2, r3);   // K = 64w+32+8q .. +8
        #pragma unroll
        for (int tl = 0; tl < 8; ++tl)
          acc[tl] = MFMA16(wfh[0][tl], a0, acc[tl]);
        #pragma unroll
        for (int tl = 0; tl < 8; ++tl)
          acc[tl] = MFMA16(wfh[1][tl], a1, acc[tl]);
      }

      // prefetch t+1 emb row (tok_n has been in flight across the poll)
      if (t < T - 1) {
        const float* ebn = emb + (size_t)tok_n * E + 32 * w + 8 * q;
        e0 = *(const float4*)ebn;
        e1 = *(const float4*)(ebn + 4);
        rr_cur = rr_n;
      }

      // gate-packed partials: lane's acc[tl] = 4 gates of (jloc=4tl+q, lc)
      // contiguous b128 writes (R4-proven)
      #pragma unroll
      for (int tl = 0; tl < 8; ++tl)
        *(f32x4*)(Pg + w * PGW + (4 * tl + q) * 64 + lc * 4) = acc[tl];
      bar_lgkm();

      // reduce (R4 map): 8 x b128 per thread + vector bias
      f32x4 g4 = *(const f32x4*)(Bias + jloc * 4);
      #pragma unroll
      for (int ww = 0; ww < 8; ++ww)
        g4 += *(const f32x4*)(Pg + ww * PGW + jloc * 64 + lc * 4);

      float ig = sigmoidf_fast(g4[0]);
      float fg = sigmoidf_fast(g4[1]);
      float gg = tanhf_fast(g4[2]);
      float og = sigmoidf_fast(g4[3]);
      float c_new = fg * carry_c + ig * gg;
      float h_new = og * tanhf_fast(c_new);
      bool live = (t < Lens[lc]);
      float h_next = live ? h_new : carry_h;   // carry regs are exact fp32
      float c_next = live ? c_new : carry_c;
      carry_h = h_next * (1.f - rr);
      carry_c = c_next * (1.f - rr);

      // remap hop: epilogue values -> LDS -> coalesced-store threads
      HX[lc * 66 + jloc] = carry_h;
      HX[lc * 66 + 33 + jloc] = h_next;
      bar_lgkm();   // also separates Pg reads from next step's writes

      // (R5 map) coalesced h broadcast + out staging
      {
        float ch = HX[bb * 66 + jj];
        float hn = HX[bb * 66 + 33 + jj];
        if (t < T - 1) {
          const uint32_t wtag = 4u | (((uint32_t)t >> 1) & 3u);
          uint32_t bits = (__builtin_bit_cast(uint32_t, ch) & ~7u) | wtag;
          const size_t doff = dstbase + (size_t)(b0 + bb) * H + khid + jj;
          st_plain(hL2 + doff, bits);   // local-L2 ack, hidden
          pend_bits = bits;             // MALL mirror deferred to next poll
          pend_doff = doff;
        }
        Obuf[ts * 512 + tid] = hn;
      }
    }
    // flush 8 steps of out: coalesced full-line stores (own-thread values)
    #pragma unroll
    for (int ts = 0; ts < 8; ++ts)
      out[((size_t)(b0 + bb) * T + (tb * 8 + ts)) * H + khid + jj] =
          Obuf[ts * 512 + tid];
  }
  // tails from epilogue-map registers (scattered 4B, once)
  out[OUT_HT + (size_t)(b0 + lc) * H + khid + jloc] = carry_h;
  out[OUT_CT + (size_t)(b0 + lc) * H + khid + jloc] = carry_c;
}

extern "C" void kernel_launch(void* const* d_in, const int* in_sizes, int n_in,
                              void* d_out, int out_size, void* d_ws, size_t ws_size,
                              hipStream_t stream) {
  const int* inputs    = (const int*)d_in[0];
  const int* lengths   = (const int*)d_in[1];
  const int* resets    = (const int*)d_in[2];
  const float* emb     = (const float*)d_in[3];
  const float* W_ih    = (const float*)d_in[4];
  const float* W_hh    = (const float*)d_in[5];
  const float* b_ih    = (const float*)d_in[6];
  const float* b_hh    = (const float*)d_in[7];
  float* out = (float*)d_out;

  // ws: [0,256K) L2-path tagged h ping-pong; [256K,512K) MALL-path
  constexpr size_t HBYTES = (size_t)2 * B * H * 4;   // 262144
  uint32_t* hL2 = (uint32_t*)d_ws;
  uint32_t* hML = (uint32_t*)((char*)d_ws + HBYTES);

  hipFuncSetAttribute((const void*)lstm_mfma,
                      hipFuncAttributeMaxDynamicSharedMemorySize, LDS_BYTES);

  hipMemsetAsync(d_ws, 0, 2 * HBYTES, stream);  // tags=0: never valid
  lstm_mfma<<<NBLK, NTHR, LDS_BYTES, stream>>>(
      inputs, lengths, resets, emb, W_ih, W_hh, b_ih, b_hh, out, hL2, hML);
}